// Round 7
// baseline (284.080 us; speedup 1.0000x reference)
//
#include <hip/hip_runtime.h>
#include <hip/hip_bf16.h>
#include <stdint.h>

#define HN     16
#define DMODEL 1024
#define DKH    64
#define SEQL   4096

typedef __attribute__((ext_vector_type(8))) short bf16x8;
typedef __attribute__((ext_vector_type(4))) float f32x4;

typedef const __attribute__((address_space(1))) uint32_t gas_u32;
typedef __attribute__((address_space(3))) uint32_t las_u32;

// async global->LDS, 16B per lane; LDS dest = wave-uniform base + lane*16
__device__ __forceinline__ void gl_lds16(const void* g, void* l) {
  __builtin_amdgcn_global_load_lds((gas_u32*)g, (las_u32*)l, 16, 0, 0);
}

__device__ __forceinline__ unsigned short f2bf(float x) {
  uint32_t u = __float_as_uint(x);
  u = (u + 0x7fffu + ((u >> 16) & 1u)) >> 16;
  return (unsigned short)u;
}

__device__ __forceinline__ uint32_t cvt_pk_bf16(float lo, float hi) {
  uint32_t r;
  asm("v_cvt_pk_bf16_f32 %0, %1, %2" : "=v"(r) : "v"(lo), "v"(hi));
  return r;
}

// raw v_exp_f32 (2^x) — single trans-pipe instruction, no ocml wrapper
__device__ __forceinline__ float fast_exp2(float x) {
  float r;
  asm("v_exp_f32 %0, %1" : "=v"(r) : "v"(x));
  return r;
}

// ---------------- fp32 -> bf16 conversion (7 tensors fused) ----------------
struct CvtArgs {
  const float *q, *k, *v, *wq, *wk, *wv, *wo;
  unsigned short *qb, *kb, *vb, *wqb, *wkb, *wvb, *wob;
};

__global__ __launch_bounds__(256) void cvt_all(CvtArgs a) {
  const int stride = gridDim.x * blockDim.x;
  for (int v4 = blockIdx.x * blockDim.x + threadIdx.x; v4 < 4194304; v4 += stride) {
    const float* sp; unsigned short* dp; int idx;
    if      (v4 < 1048576) { sp = a.q;  dp = a.qb;  idx = v4; }
    else if (v4 < 2097152) { sp = a.k;  dp = a.kb;  idx = v4 - 1048576; }
    else if (v4 < 3145728) { sp = a.v;  dp = a.vb;  idx = v4 - 2097152; }
    else if (v4 < 3407872) { sp = a.wq; dp = a.wqb; idx = v4 - 3145728; }
    else if (v4 < 3670016) { sp = a.wk; dp = a.wkb; idx = v4 - 3407872; }
    else if (v4 < 3932160) { sp = a.wv; dp = a.wvb; idx = v4 - 3670016; }
    else                   { sp = a.wo; dp = a.wob; idx = v4 - 3932160; }
    float4 f = ((const float4*)sp)[idx];
    ushort4 o;
    o.x = f2bf(f.x); o.y = f2bf(f.y); o.z = f2bf(f.z); o.w = f2bf(f.w);
    ((ushort4*)dp)[idx] = o;
  }
}

// ---------------- GEMM 128x128: C = (A * W^T + bias)*scale ------------------
// mode 0: bf16 C[M,N]; mode 1: bf16 C^T[N,M]
struct GemmDesc {
  const unsigned short* A;
  const unsigned short* W;
  const float* bias;
  void* C;
  int mode;
  float scale;
};
struct GemmArgs { GemmDesc d[3]; };

__global__ __launch_bounds__(256) void gemm_bt(GemmArgs ga) {
  const GemmDesc gd = ga.d[blockIdx.z];
  constexpr int M = SEQL, N = DMODEL, K = DMODEL;
  __shared__ unsigned short As[128 * 64];
  __shared__ unsigned short Bs[128 * 64];
  const int tid = threadIdx.x;
  const int w = tid >> 6, lane = tid & 63;
  const int g16 = lane >> 4, l16 = lane & 15;
  const int wr = w >> 1, wc = w & 1;
  const int bm0 = blockIdx.y * 128, bn0 = blockIdx.x * 128;
  const int srow = tid >> 3, scc = tid & 7;

  f32x4 acc[4][4];
#pragma unroll
  for (int i = 0; i < 4; ++i)
#pragma unroll
    for (int j = 0; j < 4; ++j)
      acc[i][j] = (f32x4){0.f, 0.f, 0.f, 0.f};

  for (int k0 = 0; k0 < K; k0 += 64) {
#pragma unroll
    for (int i = 0; i < 4; ++i) {
      int row = i * 32 + srow;
      int sw = scc ^ (row & 7);
      gl_lds16(gd.A + (size_t)(bm0 + row) * K + k0 + sw * 8,
               (void*)(As + (i * 256 + w * 64) * 8));
      gl_lds16(gd.W + (size_t)(bn0 + row) * K + k0 + sw * 8,
               (void*)(Bs + (i * 256 + w * 64) * 8));
    }
    __syncthreads();
#pragma unroll
    for (int ks = 0; ks < 2; ++ks) {
      bf16x8 af[4], bfr[4];
#pragma unroll
      for (int mt = 0; mt < 4; ++mt) {
        int row = wr * 64 + mt * 16 + l16;
        af[mt] = *(const bf16x8*)&As[row * 64 + (((ks * 4 + g16) ^ (row & 7)) * 8)];
      }
#pragma unroll
      for (int nt = 0; nt < 4; ++nt) {
        int row = wc * 64 + nt * 16 + l16;
        bfr[nt] = *(const bf16x8*)&Bs[row * 64 + (((ks * 4 + g16) ^ (row & 7)) * 8)];
      }
#pragma unroll
      for (int mt = 0; mt < 4; ++mt)
#pragma unroll
        for (int nt = 0; nt < 4; ++nt)
          acc[mt][nt] = __builtin_amdgcn_mfma_f32_16x16x32_bf16(af[mt], bfr[nt], acc[mt][nt], 0, 0, 0);
    }
    __syncthreads();
  }

  // epilogue: C/D layout col=lane&15, row=(lane>>4)*4+reg
#pragma unroll
  for (int nt = 0; nt < 4; ++nt) {
    int col = bn0 + wc * 64 + nt * 16 + l16;
    float bcol = gd.bias[col];
#pragma unroll
    for (int mt = 0; mt < 4; ++mt) {
      int row0 = bm0 + wr * 64 + mt * 16 + g16 * 4;
      f32x4 a = acc[mt][nt];
      if (gd.mode == 0) {
        unsigned short* CB = (unsigned short*)gd.C;
#pragma unroll
        for (int r = 0; r < 4; ++r)
          CB[(size_t)(row0 + r) * N + col] = f2bf((a[r] + bcol) * gd.scale);
      } else {
        unsigned short* CT = (unsigned short*)gd.C;
        ushort4 pk;
        pk.x = f2bf(a[0] + bcol); pk.y = f2bf(a[1] + bcol);
        pk.z = f2bf(a[2] + bcol); pk.w = f2bf(a[3] + bcol);
        *(ushort4*)&CT[(size_t)col * M + row0] = pk;
      }
    }
  }
}

// ---------------- GEMM 128x64 f32-out (O-projection) ------------------------
__global__ __launch_bounds__(256) void gemm_o(
    const unsigned short* __restrict__ A, const unsigned short* __restrict__ W,
    const float* __restrict__ bias, float* __restrict__ C) {
  constexpr int N = DMODEL, K = DMODEL;
  __shared__ unsigned short As[128 * 64];
  __shared__ unsigned short Bs[64 * 64];
  const int tid = threadIdx.x;
  const int w = tid >> 6, lane = tid & 63;
  const int g16 = lane >> 4, l16 = lane & 15;
  const int wr = w >> 1, wc = w & 1;
  const int bm0 = blockIdx.y * 128, bn0 = blockIdx.x * 64;
  const int srow = tid >> 3, scc = tid & 7;

  f32x4 acc[4][2];
#pragma unroll
  for (int i = 0; i < 4; ++i)
#pragma unroll
    for (int j = 0; j < 2; ++j)
      acc[i][j] = (f32x4){0.f, 0.f, 0.f, 0.f};

  for (int k0 = 0; k0 < K; k0 += 64) {
#pragma unroll
    for (int i = 0; i < 4; ++i) {
      int row = i * 32 + srow;
      int sw = scc ^ (row & 7);
      gl_lds16(A + (size_t)(bm0 + row) * K + k0 + sw * 8,
               (void*)(As + (i * 256 + w * 64) * 8));
    }
#pragma unroll
    for (int i = 0; i < 2; ++i) {
      int row = i * 32 + srow;
      int sw = scc ^ (row & 7);
      gl_lds16(W + (size_t)(bn0 + row) * K + k0 + sw * 8,
               (void*)(Bs + (i * 256 + w * 64) * 8));
    }
    __syncthreads();
#pragma unroll
    for (int ks = 0; ks < 2; ++ks) {
      bf16x8 af[4], bfr[2];
#pragma unroll
      for (int mt = 0; mt < 4; ++mt) {
        int row = wr * 64 + mt * 16 + l16;
        af[mt] = *(const bf16x8*)&As[row * 64 + (((ks * 4 + g16) ^ (row & 7)) * 8)];
      }
#pragma unroll
      for (int nt = 0; nt < 2; ++nt) {
        int row = wc * 32 + nt * 16 + l16;
        bfr[nt] = *(const bf16x8*)&Bs[row * 64 + (((ks * 4 + g16) ^ (row & 7)) * 8)];
      }
#pragma unroll
      for (int mt = 0; mt < 4; ++mt)
#pragma unroll
        for (int nt = 0; nt < 2; ++nt)
          acc[mt][nt] = __builtin_amdgcn_mfma_f32_16x16x32_bf16(af[mt], bfr[nt], acc[mt][nt], 0, 0, 0);
    }
    __syncthreads();
  }

#pragma unroll
  for (int nt = 0; nt < 2; ++nt) {
    int col = bn0 + wc * 32 + nt * 16 + l16;
    float bcol = bias[col];
#pragma unroll
    for (int mt = 0; mt < 4; ++mt) {
      int row0 = bm0 + wr * 64 + mt * 16 + g16 * 4;
#pragma unroll
      for (int r = 0; r < 4; ++r)
        C[(size_t)(row0 + r) * N + col] = acc[mt][nt][r] + bcol;
    }
  }
}

// ---------------- flash attention ----------------
// grid (SEQ/128, H, NZ); 4 waves/block; wave owns 32 q-rows.
// PARTIAL=true: block handles a 2048-wide KV slice (z selects), writes fp32
// unnormalized O~ + (l,m) per row -> 2x blocks, 3 blocks/CU occupancy.
// PARTIAL=false: full KV range, writes normalized bf16 (round-5 verified path).
template<bool PARTIAL>
__global__ __launch_bounds__(256, 3) void attn_fwd(
    const unsigned short* __restrict__ Qm, const unsigned short* __restrict__ Km,
    const unsigned short* __restrict__ Vtm, unsigned short* __restrict__ Xm,
    float* __restrict__ Opart, float* __restrict__ Lbuf) {
  __shared__ __align__(16) unsigned short Ksm[2 * 4096];
  __shared__ __align__(16) unsigned short Vsm[2 * 4096];
  __shared__ __align__(16) unsigned short Psm[8192];
  const int tid = threadIdx.x;
  const int w = tid >> 6, lane = tid & 63;
  const int g = lane >> 4, qi = lane & 15;
  const int hb = blockIdx.y * DKH;
  const int q0 = blockIdx.x * 128 + w * 32;
  const int kv0 = PARTIAL ? blockIdx.z * 2048 : 0;
  const int NKV = PARTIAL ? 32 : 64;  // KV tiles of 64
  const int srow = tid >> 3, scc = tid & 7;
  const float THR = 12.0f;

  // staging source pointers (first tile of slice), pre-swizzled chunks
  const int r0 = srow, r1 = 32 + srow;
  const unsigned short* kp0 = Km + (size_t)(kv0 + r0) * DMODEL + hb + (scc ^ (r0 & 7)) * 8;
  const unsigned short* kp1 = Km + (size_t)(kv0 + r1) * DMODEL + hb + (scc ^ (r1 & 7)) * 8;
  const unsigned short* vp0 = Vtm + (size_t)(hb + r0) * SEQL + kv0 + (scc ^ (r0 & 7)) * 8;
  const unsigned short* vp1 = Vtm + (size_t)(hb + r1) * SEQL + kv0 + (scc ^ (r1 & 7)) * 8;
  unsigned short* kd0 = Ksm + (w * 64) * 8;
  unsigned short* kd1 = Ksm + (256 + w * 64) * 8;
  unsigned short* vd0 = Vsm + (w * 64) * 8;
  unsigned short* vd1 = Vsm + (256 + w * 64) * 8;

  // loop-invariant LDS read bases (row = sub*16 + qi => row&7 == qi&7)
  const unsigned short* kb0 = &Ksm[qi * 64 + (((0 + g) ^ (qi & 7)) * 8)];
  const unsigned short* kb1 = &Ksm[qi * 64 + (((4 + g) ^ (qi & 7)) * 8)];
  const unsigned short* vrb0 = &Vsm[qi * 64 + (((0 + g) ^ (qi & 7)) * 8)];
  const unsigned short* vrb1 = &Vsm[qi * 64 + (((4 + g) ^ (qi & 7)) * 8)];

  // P-LDS addresses; wave slice 2048 shorts, q-group h adds 1024 shorts
  const int pwb = w * 2048 + qi * 64 + (g & 1) * 4;
  const int pw0 = pwb + (((0 + (g >> 1)) ^ (qi & 7)) * 8);
  const int pw1 = pwb + (((2 + (g >> 1)) ^ (qi & 7)) * 8);
  const int pw2 = pwb + (((4 + (g >> 1)) ^ (qi & 7)) * 8);
  const int pw3 = pwb + (((6 + (g >> 1)) ^ (qi & 7)) * 8);
  const unsigned short* prb0 = &Psm[w * 2048 + qi * 64 + (((0 + g) ^ (qi & 7)) * 8)];
  const unsigned short* prb1 = &Psm[w * 2048 + qi * 64 + (((4 + g) ^ (qi & 7)) * 8)];

  // ones B-fragment for the denominator MFMA
  union { uint32_t u[4]; bf16x8 v; } onef;
  onef.u[0] = onef.u[1] = onef.u[2] = onef.u[3] = 0x3F803F80u;

  // Q fragments: lane holds Q[q0 + h*16 + qi][k = ks*32 + g*8 + j]
  bf16x8 qf[2][2];
#pragma unroll
  for (int h = 0; h < 2; ++h)
#pragma unroll
    for (int ks = 0; ks < 2; ++ks)
      qf[h][ks] = *(const bf16x8*)&Qm[(size_t)(q0 + h * 16 + qi) * DMODEL + hb + ks * 32 + g * 8];

  f32x4 oacc[2][4];
#pragma unroll
  for (int h = 0; h < 2; ++h)
#pragma unroll
    for (int i = 0; i < 4; ++i) oacc[h][i] = (f32x4){0.f, 0.f, 0.f, 0.f};
  f32x4 lacc[2];
  lacc[0] = lacc[1] = (f32x4){0.f, 0.f, 0.f, 0.f};
  float mrun[2] = {-1e30f, -1e30f};

  // prologue: stage first tile into buf 0.  NOTE: the final prefetches march
  // up to 2 tiles past the slice end; those reads land in the adjacent ws
  // regions (Kp->Vtp, Vtp->Xp), which are mapped — garbage data, never used.
  gl_lds16(kp0, kd0); gl_lds16(kp1, kd1);
  gl_lds16(vp0, vd0); gl_lds16(vp1, vd1);
  kp0 += 64 * DMODEL; kp1 += 64 * DMODEL; vp0 += 64; vp1 += 64;
  asm volatile("s_waitcnt vmcnt(0)" ::: "memory");
  __builtin_amdgcn_s_barrier();

#define ATTN_STEP(BUF)                                                         \
  do {                                                                         \
    gl_lds16(kp0, kd0 + ((BUF) ^ 1) * 4096);                                   \
    gl_lds16(kp1, kd1 + ((BUF) ^ 1) * 4096);                                   \
    gl_lds16(vp0, vd0 + ((BUF) ^ 1) * 4096);                                   \
    gl_lds16(vp1, vd1 + ((BUF) ^ 1) * 4096);                                   \
    kp0 += 64 * DMODEL; kp1 += 64 * DMODEL; vp0 += 64; vp1 += 64;              \
    f32x4 sv[2][4];                                                            \
    _Pragma("unroll")                                                          \
    for (int h = 0; h < 2; ++h)                                                \
      _Pragma("unroll")                                                        \
      for (int kvt = 0; kvt < 4; ++kvt) sv[h][kvt] = (f32x4){0.f, 0.f, 0.f, 0.f}; \
    __builtin_amdgcn_s_setprio(1);                                             \
    _Pragma("unroll")                                                          \
    for (int kvt = 0; kvt < 4; ++kvt) {                                        \
      bf16x8 ka0 = *(const bf16x8*)(kb0 + (BUF) * 4096 + kvt * 1024);          \
      bf16x8 ka1 = *(const bf16x8*)(kb1 + (BUF) * 4096 + kvt * 1024);          \
      _Pragma("unroll")                                                        \
      for (int h = 0; h < 2; ++h) {                                            \
        sv[h][kvt] = __builtin_amdgcn_mfma_f32_16x16x32_bf16(ka0, qf[h][0], sv[h][kvt], 0, 0, 0); \
        sv[h][kvt] = __builtin_amdgcn_mfma_f32_16x16x32_bf16(ka1, qf[h][1], sv[h][kvt], 0, 0, 0); \
      }                                                                        \
    }                                                                          \
    __builtin_amdgcn_s_setprio(0);                                             \
    float tmax[2];                                                             \
    _Pragma("unroll")                                                          \
    for (int h = 0; h < 2; ++h) {                                              \
      float tm = sv[h][0][0];                                                  \
      _Pragma("unroll")                                                        \
      for (int kvt = 0; kvt < 4; ++kvt)                                        \
        _Pragma("unroll")                                                      \
        for (int r = 0; r < 4; ++r) tm = fmaxf(tm, sv[h][kvt][r]);             \
      tm = fmaxf(tm, __shfl_xor(tm, 16));                                      \
      tm = fmaxf(tm, __shfl_xor(tm, 32));                                      \
      tmax[h] = tm;                                                            \
    }                                                                          \
    float need = fmaxf(tmax[0] - mrun[0], tmax[1] - mrun[1]);                  \
    if (__any(need > THR)) {                                                   \
      _Pragma("unroll")                                                        \
      for (int h = 0; h < 2; ++h) {                                            \
        float mnew = fmaxf(mrun[h], tmax[h]);                                  \
        float alpha = fast_exp2(mrun[h] - mnew);                               \
        _Pragma("unroll")                                                      \
        for (int r = 0; r < 4; ++r) {                                          \
          float ar = __shfl(alpha, (lane & 48) + g * 4 + r);                   \
          lacc[h][r] *= ar;                                                    \
          _Pragma("unroll")                                                    \
          for (int dg = 0; dg < 4; ++dg) oacc[h][dg][r] *= ar;                 \
        }                                                                      \
        mrun[h] = mnew;                                                        \
      }                                                                        \
    }                                                                          \
    _Pragma("unroll")                                                          \
    for (int h = 0; h < 2; ++h) {                                              \
      float p[16];                                                             \
      _Pragma("unroll")                                                        \
      for (int kvt = 0; kvt < 4; ++kvt)                                        \
        _Pragma("unroll")                                                      \
        for (int r = 0; r < 4; ++r)                                            \
          p[kvt * 4 + r] = fast_exp2(sv[h][kvt][r] - mrun[h]);                 \
      uint2 pk;                                                                \
      pk.x = cvt_pk_bf16(p[0], p[1]);  pk.y = cvt_pk_bf16(p[2], p[3]);         \
      *(uint2*)&Psm[pw0 + h * 1024] = pk;                                      \
      pk.x = cvt_pk_bf16(p[4], p[5]);  pk.y = cvt_pk_bf16(p[6], p[7]);         \
      *(uint2*)&Psm[pw1 + h * 1024] = pk;                                      \
      pk.x = cvt_pk_bf16(p[8], p[9]);  pk.y = cvt_pk_bf16(p[10], p[11]);       \
      *(uint2*)&Psm[pw2 + h * 1024] = pk;                                      \
      pk.x = cvt_pk_bf16(p[12], p[13]); pk.y = cvt_pk_bf16(p[14], p[15]);      \
      *(uint2*)&Psm[pw3 + h * 1024] = pk;                                      \
    }                                                                          \
    bf16x8 pa[2][2];                                                           \
    _Pragma("unroll")                                                          \
    for (int h = 0; h < 2; ++h) {                                              \
      pa[h][0] = *(const bf16x8*)(prb0 + h * 1024);                            \
      pa[h][1] = *(const bf16x8*)(prb1 + h * 1024);                            \
    }                                                                          \
    __builtin_amdgcn_s_setprio(1);                                             \
    _Pragma("unroll")                                                          \
    for (int h = 0; h < 2; ++h) {                                              \
      lacc[h] = __builtin_amdgcn_mfma_f32_16x16x32_bf16(pa[h][0], onef.v, lacc[h], 0, 0, 0); \
      lacc[h] = __builtin_amdgcn_mfma_f32_16x16x32_bf16(pa[h][1], onef.v, lacc[h], 0, 0, 0); \
    }                                                                          \
    _Pragma("unroll")                                                          \
    for (int dg = 0; dg < 4; ++dg) {                                           \
      bf16x8 vb0 = *(const bf16x8*)(vrb0 + (BUF) * 4096 + dg * 1024);          \
      bf16x8 vb1 = *(const bf16x8*)(vrb1 + (BUF) * 4096 + dg * 1024);          \
      _Pragma("unroll")                                                        \
      for (int h = 0; h < 2; ++h) {                                            \
        oacc[h][dg] = __builtin_amdgcn_mfma_f32_16x16x32_bf16(pa[h][0], vb0, oacc[h][dg], 0, 0, 0); \
        oacc[h][dg] = __builtin_amdgcn_mfma_f32_16x16x32_bf16(pa[h][1], vb1, oacc[h][dg], 0, 0, 0); \
      }                                                                        \
    }                                                                          \
    __builtin_amdgcn_s_setprio(0);                                             \
    asm volatile("s_waitcnt vmcnt(0)" ::: "memory");                           \
    __builtin_amdgcn_s_barrier();                                              \
  } while (0)

  for (int tt = 0; tt < NKV / 2; ++tt) {
    ATTN_STEP(0);
    ATTN_STEP(1);
  }
#undef ATTN_STEP

  if constexpr (PARTIAL) {
    float* Op = Opart + (size_t)blockIdx.z * (SEQL * DMODEL);
    float* Lp = Lbuf + (size_t)blockIdx.z * (SEQL * HN * 2);
#pragma unroll
    for (int h = 0; h < 2; ++h)
#pragma unroll
      for (int r = 0; r < 4; ++r) {
        int row = q0 + h * 16 + g * 4 + r;
        float msh = __shfl(mrun[h], (lane & 48) + g * 4 + r); // all lanes exec
#pragma unroll
        for (int dg = 0; dg < 4; ++dg)
          Op[(size_t)row * DMODEL + hb + dg * 16 + qi] = oacc[h][dg][r];
        if (qi == 0) {
          Lp[(row * HN + blockIdx.y) * 2]     = lacc[h][r];
          Lp[(row * HN + blockIdx.y) * 2 + 1] = msh;
        }
      }
  } else {
#pragma unroll
    for (int h = 0; h < 2; ++h)
#pragma unroll
      for (int r = 0; r < 4; ++r) {
        float inv = 1.f / lacc[h][r];
        int row = q0 + h * 16 + g * 4 + r;
#pragma unroll
        for (int dg = 0; dg < 4; ++dg)
          Xm[(size_t)row * DMODEL + hb + dg * 16 + qi] = f2bf(oacc[h][dg][r] * inv);
      }
  }
}

// ---------------- combine the two KV-half partials -> bf16 Xp ---------------
// needs SEQL*DMODEL/4 threads = 4096 blocks x 256 (R6 bug: launched 1024)
__global__ __launch_bounds__(256) void attn_combine(
    const float* __restrict__ Opart, const float* __restrict__ Lbuf,
    unsigned short* __restrict__ Xm) {
  const int idx4 = blockIdx.x * 256 + threadIdx.x;   // 1048576 threads
  const int row = idx4 >> 8;
  const int col = (idx4 & 255) * 4;                  // 4 cols, same head
  const int head = col >> 6;
  float2 lm0 = ((const float2*)Lbuf)[row * HN + head];
  float2 lm1 = ((const float2*)(Lbuf + SEQL * HN * 2))[row * HN + head];
  float m = fmaxf(lm0.y, lm1.y);
  float w0 = fast_exp2(lm0.y - m), w1 = fast_exp2(lm1.y - m);
  float inv = 1.f / (lm0.x * w0 + lm1.x * w1);
  float4 o0 = *(const float4*)&Opart[(size_t)row * DMODEL + col];
  float4 o1 = *(const float4*)&Opart[(size_t)SEQL * DMODEL + (size_t)row * DMODEL + col];
  ushort4 res;
  res.x = f2bf((o0.x * w0 + o1.x * w1) * inv);
  res.y = f2bf((o0.y * w0 + o1.y * w1) * inv);
  res.z = f2bf((o0.z * w0 + o1.z * w1) * inv);
  res.w = f2bf((o0.w * w0 + o1.w * w1) * inv);
  *(ushort4*)&Xm[(size_t)row * DMODEL + col] = res;
}

// ---------------- launch ----------------
extern "C" void kernel_launch(void* const* d_in, const int* in_sizes, int n_in,
                              void* d_out, int out_size, void* d_ws, size_t ws_size,
                              hipStream_t stream) {
  const float* query = (const float*)d_in[0];
  const float* key_  = (const float*)d_in[1];
  const float* value = (const float*)d_in[2];
  const float* Wq = (const float*)d_in[3];
  const float* bq = (const float*)d_in[4];
  const float* Wk = (const float*)d_in[5];
  const float* bk = (const float*)d_in[6];
  const float* Wv = (const float*)d_in[7];
  const float* bv = (const float*)d_in[8];
  const float* Wo = (const float*)d_in[9];
  const float* bo = (const float*)d_in[10];

  char* ws = (char*)d_ws;
  const size_t MB = 1024 * 1024;
  unsigned short* qb  = (unsigned short*)(ws + 0 * MB);
  unsigned short* kb  = (unsigned short*)(ws + 8 * MB);
  unsigned short* vb  = (unsigned short*)(ws + 16 * MB);
  unsigned short* wqb = (unsigned short*)(ws + 24 * MB);
  unsigned short* wkb = (unsigned short*)(ws + 26 * MB);
  unsigned short* wvb = (unsigned short*)(ws + 28 * MB);
  unsigned short* wob = (unsigned short*)(ws + 30 * MB);
  unsigned short* Qp  = (unsigned short*)(ws + 32 * MB);
  unsigned short* Kp  = (unsigned short*)(ws + 40 * MB);
  unsigned short* Vtp = (unsigned short*)(ws + 48 * MB);
  unsigned short* Xp  = (unsigned short*)(ws + 56 * MB);
  float* Opart = (float*)(ws + 64 * MB);   // 2 x 16 MB (split path only)
  float* Lbuf  = (float*)(ws + 96 * MB);   // 2 x 512 KB (split path only)

  CvtArgs ca{query, key_, value, Wq, Wk, Wv, Wo, qb, kb, vb, wqb, wkb, wvb, wob};
  cvt_all<<<dim3(2048), dim3(256), 0, stream>>>(ca);

  const float CE = 0.18033688011112042f; // log2(e)/sqrt(64)
  GemmArgs gp;
  gp.d[0] = GemmDesc{qb, wqb, bq, (void*)Qp, 0, CE};   // Q pre-scaled
  gp.d[1] = GemmDesc{kb, wkb, bk, (void*)Kp, 0, 1.0f};
  gp.d[2] = GemmDesc{vb, wvb, bv, (void*)Vtp, 1, 1.0f}; // V transposed [d][s]
  gemm_bt<<<dim3(8, 32, 3), dim3(256), 0, stream>>>(gp);

  if (ws_size >= 98 * MB) {
    // KV-split x2: 1024 blocks -> 3 blocks/CU (vs 2), partials + combine
    attn_fwd<true><<<dim3(SEQL / 128, HN, 2), dim3(256), 0, stream>>>(
        Qp, Kp, Vtp, nullptr, Opart, Lbuf);
    attn_combine<<<dim3(4096), dim3(256), 0, stream>>>(Opart, Lbuf, Xp);
  } else {
    attn_fwd<false><<<dim3(SEQL / 128, HN, 1), dim3(256), 0, stream>>>(
        Qp, Kp, Vtp, Xp, nullptr, nullptr);
  }

  gemm_o<<<dim3(16, 32), dim3(256), 0, stream>>>(Xp, wob, bo, (float*)d_out);
}

// Round 8
// 283.340 us; speedup vs baseline: 1.0026x; 1.0026x over previous
//
#include <hip/hip_runtime.h>
#include <hip/hip_bf16.h>
#include <stdint.h>

#define HN     16
#define DMODEL 1024
#define DKH    64
#define SEQL   4096

typedef __attribute__((ext_vector_type(8))) short bf16x8;
typedef __attribute__((ext_vector_type(4))) float f32x4;

typedef const __attribute__((address_space(1))) uint32_t gas_u32;
typedef __attribute__((address_space(3))) uint32_t las_u32;

// async global->LDS, 16B per lane; LDS dest = wave-uniform base + lane*16
__device__ __forceinline__ void gl_lds16(const void* g, void* l) {
  __builtin_amdgcn_global_load_lds((gas_u32*)g, (las_u32*)l, 16, 0, 0);
}

__device__ __forceinline__ unsigned short f2bf(float x) {
  uint32_t u = __float_as_uint(x);
  u = (u + 0x7fffu + ((u >> 16) & 1u)) >> 16;
  return (unsigned short)u;
}

__device__ __forceinline__ uint32_t cvt_pk_bf16(float lo, float hi) {
  uint32_t r;
  asm("v_cvt_pk_bf16_f32 %0, %1, %2" : "=v"(r) : "v"(lo), "v"(hi));
  return r;
}

// raw v_exp_f32 (2^x) — single trans-pipe instruction, no ocml wrapper
__device__ __forceinline__ float fast_exp2(float x) {
  float r;
  asm("v_exp_f32 %0, %1" : "=v"(r) : "v"(x));
  return r;
}

// ---------------- fp32 -> bf16 conversion (7 tensors fused) ----------------
struct CvtArgs {
  const float *q, *k, *v, *wq, *wk, *wv, *wo;
  unsigned short *qb, *kb, *vb, *wqb, *wkb, *wvb, *wob;
};

__global__ __launch_bounds__(256) void cvt_all(CvtArgs a) {
  const int stride = gridDim.x * blockDim.x;
  for (int v4 = blockIdx.x * blockDim.x + threadIdx.x; v4 < 4194304; v4 += stride) {
    const float* sp; unsigned short* dp; int idx;
    if      (v4 < 1048576) { sp = a.q;  dp = a.qb;  idx = v4; }
    else if (v4 < 2097152) { sp = a.k;  dp = a.kb;  idx = v4 - 1048576; }
    else if (v4 < 3145728) { sp = a.v;  dp = a.vb;  idx = v4 - 2097152; }
    else if (v4 < 3407872) { sp = a.wq; dp = a.wqb; idx = v4 - 3145728; }
    else if (v4 < 3670016) { sp = a.wk; dp = a.wkb; idx = v4 - 3407872; }
    else if (v4 < 3932160) { sp = a.wv; dp = a.wvb; idx = v4 - 3670016; }
    else                   { sp = a.wo; dp = a.wob; idx = v4 - 3932160; }
    float4 f = ((const float4*)sp)[idx];
    ushort4 o;
    o.x = f2bf(f.x); o.y = f2bf(f.y); o.z = f2bf(f.z); o.w = f2bf(f.w);
    ((ushort4*)dp)[idx] = o;
  }
}

// ---------------- GEMM 128x128: C = (A * W^T + bias)*scale ------------------
// mode 0: bf16 C[M,N]; mode 1: bf16 C^T[N,M]
struct GemmDesc {
  const unsigned short* A;
  const unsigned short* W;
  const float* bias;
  void* C;
  int mode;
  float scale;
};
struct GemmArgs { GemmDesc d[3]; };

__global__ __launch_bounds__(256) void gemm_bt(GemmArgs ga) {
  const GemmDesc gd = ga.d[blockIdx.z];
  constexpr int M = SEQL, N = DMODEL, K = DMODEL;
  __shared__ unsigned short As[128 * 64];
  __shared__ unsigned short Bs[128 * 64];
  const int tid = threadIdx.x;
  const int w = tid >> 6, lane = tid & 63;
  const int g16 = lane >> 4, l16 = lane & 15;
  const int wr = w >> 1, wc = w & 1;
  const int bm0 = blockIdx.y * 128, bn0 = blockIdx.x * 128;
  const int srow = tid >> 3, scc = tid & 7;

  f32x4 acc[4][4];
#pragma unroll
  for (int i = 0; i < 4; ++i)
#pragma unroll
    for (int j = 0; j < 4; ++j)
      acc[i][j] = (f32x4){0.f, 0.f, 0.f, 0.f};

  for (int k0 = 0; k0 < K; k0 += 64) {
#pragma unroll
    for (int i = 0; i < 4; ++i) {
      int row = i * 32 + srow;
      int sw = scc ^ (row & 7);
      gl_lds16(gd.A + (size_t)(bm0 + row) * K + k0 + sw * 8,
               (void*)(As + (i * 256 + w * 64) * 8));
      gl_lds16(gd.W + (size_t)(bn0 + row) * K + k0 + sw * 8,
               (void*)(Bs + (i * 256 + w * 64) * 8));
    }
    __syncthreads();
#pragma unroll
    for (int ks = 0; ks < 2; ++ks) {
      bf16x8 af[4], bfr[4];
#pragma unroll
      for (int mt = 0; mt < 4; ++mt) {
        int row = wr * 64 + mt * 16 + l16;
        af[mt] = *(const bf16x8*)&As[row * 64 + (((ks * 4 + g16) ^ (row & 7)) * 8)];
      }
#pragma unroll
      for (int nt = 0; nt < 4; ++nt) {
        int row = wc * 64 + nt * 16 + l16;
        bfr[nt] = *(const bf16x8*)&Bs[row * 64 + (((ks * 4 + g16) ^ (row & 7)) * 8)];
      }
#pragma unroll
      for (int mt = 0; mt < 4; ++mt)
#pragma unroll
        for (int nt = 0; nt < 4; ++nt)
          acc[mt][nt] = __builtin_amdgcn_mfma_f32_16x16x32_bf16(af[mt], bfr[nt], acc[mt][nt], 0, 0, 0);
    }
    __syncthreads();
  }

  // epilogue: C/D layout col=lane&15, row=(lane>>4)*4+reg
#pragma unroll
  for (int nt = 0; nt < 4; ++nt) {
    int col = bn0 + wc * 64 + nt * 16 + l16;
    float bcol = gd.bias[col];
#pragma unroll
    for (int mt = 0; mt < 4; ++mt) {
      int row0 = bm0 + wr * 64 + mt * 16 + g16 * 4;
      f32x4 a = acc[mt][nt];
      if (gd.mode == 0) {
        unsigned short* CB = (unsigned short*)gd.C;
#pragma unroll
        for (int r = 0; r < 4; ++r)
          CB[(size_t)(row0 + r) * N + col] = f2bf((a[r] + bcol) * gd.scale);
      } else {
        unsigned short* CT = (unsigned short*)gd.C;
        ushort4 pk;
        pk.x = f2bf(a[0] + bcol); pk.y = f2bf(a[1] + bcol);
        pk.z = f2bf(a[2] + bcol); pk.w = f2bf(a[3] + bcol);
        *(ushort4*)&CT[(size_t)col * M + row0] = pk;
      }
    }
  }
}

// ---------------- GEMM 128x64 f32-out (O-projection) ------------------------
__global__ __launch_bounds__(256) void gemm_o(
    const unsigned short* __restrict__ A, const unsigned short* __restrict__ W,
    const float* __restrict__ bias, float* __restrict__ C) {
  constexpr int N = DMODEL, K = DMODEL;
  __shared__ unsigned short As[128 * 64];
  __shared__ unsigned short Bs[64 * 64];
  const int tid = threadIdx.x;
  const int w = tid >> 6, lane = tid & 63;
  const int g16 = lane >> 4, l16 = lane & 15;
  const int wr = w >> 1, wc = w & 1;
  const int bm0 = blockIdx.y * 128, bn0 = blockIdx.x * 64;
  const int srow = tid >> 3, scc = tid & 7;

  f32x4 acc[4][2];
#pragma unroll
  for (int i = 0; i < 4; ++i)
#pragma unroll
    for (int j = 0; j < 2; ++j)
      acc[i][j] = (f32x4){0.f, 0.f, 0.f, 0.f};

  for (int k0 = 0; k0 < K; k0 += 64) {
#pragma unroll
    for (int i = 0; i < 4; ++i) {
      int row = i * 32 + srow;
      int sw = scc ^ (row & 7);
      gl_lds16(A + (size_t)(bm0 + row) * K + k0 + sw * 8,
               (void*)(As + (i * 256 + w * 64) * 8));
    }
#pragma unroll
    for (int i = 0; i < 2; ++i) {
      int row = i * 32 + srow;
      int sw = scc ^ (row & 7);
      gl_lds16(W + (size_t)(bn0 + row) * K + k0 + sw * 8,
               (void*)(Bs + (i * 256 + w * 64) * 8));
    }
    __syncthreads();
#pragma unroll
    for (int ks = 0; ks < 2; ++ks) {
      bf16x8 af[4], bfr[2];
#pragma unroll
      for (int mt = 0; mt < 4; ++mt) {
        int row = wr * 64 + mt * 16 + l16;
        af[mt] = *(const bf16x8*)&As[row * 64 + (((ks * 4 + g16) ^ (row & 7)) * 8)];
      }
#pragma unroll
      for (int nt = 0; nt < 2; ++nt) {
        int row = wc * 32 + nt * 16 + l16;
        bfr[nt] = *(const bf16x8*)&Bs[row * 64 + (((ks * 4 + g16) ^ (row & 7)) * 8)];
      }
#pragma unroll
      for (int mt = 0; mt < 4; ++mt)
#pragma unroll
        for (int nt = 0; nt < 2; ++nt)
          acc[mt][nt] = __builtin_amdgcn_mfma_f32_16x16x32_bf16(af[mt], bfr[nt], acc[mt][nt], 0, 0, 0);
    }
    __syncthreads();
  }

#pragma unroll
  for (int nt = 0; nt < 2; ++nt) {
    int col = bn0 + wc * 32 + nt * 16 + l16;
    float bcol = bias[col];
#pragma unroll
    for (int mt = 0; mt < 4; ++mt) {
      int row0 = bm0 + wr * 64 + mt * 16 + g16 * 4;
#pragma unroll
      for (int r = 0; r < 4; ++r)
        C[(size_t)(row0 + r) * N + col] = acc[mt][nt][r] + bcol;
    }
  }
}

// ---------------- flash attention ----------------
// grid (SEQ/128, H, NZ); 4 waves/block; wave owns 32 q-rows.
// LDS = 40960 B exactly -> 4 blocks/CU (160 KiB full): the 8KB P-transpose
// scratch is time-shared between the two h-groups (DS ops of a wave execute
// in order -> no hazard, no barrier).
// PARTIAL=true: block handles a 2048-wide KV slice, writes fp32 O~ + (l,m).
template<bool PARTIAL>
__global__ __launch_bounds__(256, 4) void attn_fwd(
    const unsigned short* __restrict__ Qm, const unsigned short* __restrict__ Km,
    const unsigned short* __restrict__ Vtm, unsigned short* __restrict__ Xm,
    float* __restrict__ Opart, float* __restrict__ Lbuf) {
  __shared__ __align__(16) unsigned short Ksm[2 * 4096];
  __shared__ __align__(16) unsigned short Vsm[2 * 4096];
  __shared__ __align__(16) unsigned short Psm[4096];
  const int tid = threadIdx.x;
  const int w = tid >> 6, lane = tid & 63;
  const int g = lane >> 4, qi = lane & 15;
  const int hb = blockIdx.y * DKH;
  const int q0 = blockIdx.x * 128 + w * 32;
  const int kv0 = PARTIAL ? blockIdx.z * 2048 : 0;
  const int NKV = PARTIAL ? 32 : 64;  // KV tiles of 64
  const int srow = tid >> 3, scc = tid & 7;
  const float THR = 12.0f;

  // staging source pointers (first tile of slice), pre-swizzled chunks
  const int r0 = srow, r1 = 32 + srow;
  const unsigned short* kp0 = Km + (size_t)(kv0 + r0) * DMODEL + hb + (scc ^ (r0 & 7)) * 8;
  const unsigned short* kp1 = Km + (size_t)(kv0 + r1) * DMODEL + hb + (scc ^ (r1 & 7)) * 8;
  const unsigned short* vp0 = Vtm + (size_t)(hb + r0) * SEQL + kv0 + (scc ^ (r0 & 7)) * 8;
  const unsigned short* vp1 = Vtm + (size_t)(hb + r1) * SEQL + kv0 + (scc ^ (r1 & 7)) * 8;
  unsigned short* kd0 = Ksm + (w * 64) * 8;
  unsigned short* kd1 = Ksm + (256 + w * 64) * 8;
  unsigned short* vd0 = Vsm + (w * 64) * 8;
  unsigned short* vd1 = Vsm + (256 + w * 64) * 8;

  // loop-invariant LDS read bases (row = sub*16 + qi => row&7 == qi&7)
  const unsigned short* kb0 = &Ksm[qi * 64 + (((0 + g) ^ (qi & 7)) * 8)];
  const unsigned short* kb1 = &Ksm[qi * 64 + (((4 + g) ^ (qi & 7)) * 8)];
  const unsigned short* vrb0 = &Vsm[qi * 64 + (((0 + g) ^ (qi & 7)) * 8)];
  const unsigned short* vrb1 = &Vsm[qi * 64 + (((4 + g) ^ (qi & 7)) * 8)];

  // P-LDS addresses; wave slice 1024 shorts, time-shared by both h-groups
  const int pwb = w * 1024 + qi * 64 + (g & 1) * 4;
  const int pw0 = pwb + (((0 + (g >> 1)) ^ (qi & 7)) * 8);
  const int pw1 = pwb + (((2 + (g >> 1)) ^ (qi & 7)) * 8);
  const int pw2 = pwb + (((4 + (g >> 1)) ^ (qi & 7)) * 8);
  const int pw3 = pwb + (((6 + (g >> 1)) ^ (qi & 7)) * 8);
  const unsigned short* prb0 = &Psm[w * 1024 + qi * 64 + (((0 + g) ^ (qi & 7)) * 8)];
  const unsigned short* prb1 = &Psm[w * 1024 + qi * 64 + (((4 + g) ^ (qi & 7)) * 8)];

  // ones B-fragment for the denominator MFMA
  union { uint32_t u[4]; bf16x8 v; } onef;
  onef.u[0] = onef.u[1] = onef.u[2] = onef.u[3] = 0x3F803F80u;

  // Q fragments: lane holds Q[q0 + h*16 + qi][k = ks*32 + g*8 + j]
  bf16x8 qf[2][2];
#pragma unroll
  for (int h = 0; h < 2; ++h)
#pragma unroll
    for (int ks = 0; ks < 2; ++ks)
      qf[h][ks] = *(const bf16x8*)&Qm[(size_t)(q0 + h * 16 + qi) * DMODEL + hb + ks * 32 + g * 8];

  f32x4 oacc[2][4];
#pragma unroll
  for (int h = 0; h < 2; ++h)
#pragma unroll
    for (int i = 0; i < 4; ++i) oacc[h][i] = (f32x4){0.f, 0.f, 0.f, 0.f};
  f32x4 lacc[2];
  lacc[0] = lacc[1] = (f32x4){0.f, 0.f, 0.f, 0.f};
  float mrun[2] = {-1e30f, -1e30f};

  // prologue: stage first tile into buf 0.  NOTE: the final prefetches march
  // up to 2 tiles past the slice end; those reads land in the adjacent ws
  // regions, which are mapped — garbage data, never used.
  gl_lds16(kp0, kd0); gl_lds16(kp1, kd1);
  gl_lds16(vp0, vd0); gl_lds16(vp1, vd1);
  kp0 += 64 * DMODEL; kp1 += 64 * DMODEL; vp0 += 64; vp1 += 64;
  asm volatile("s_waitcnt vmcnt(0)" ::: "memory");
  __builtin_amdgcn_s_barrier();

#define ATTN_STEP(BUF)                                                         \
  do {                                                                         \
    gl_lds16(kp0, kd0 + ((BUF) ^ 1) * 4096);                                   \
    gl_lds16(kp1, kd1 + ((BUF) ^ 1) * 4096);                                   \
    gl_lds16(vp0, vd0 + ((BUF) ^ 1) * 4096);                                   \
    gl_lds16(vp1, vd1 + ((BUF) ^ 1) * 4096);                                   \
    kp0 += 64 * DMODEL; kp1 += 64 * DMODEL; vp0 += 64; vp1 += 64;              \
    f32x4 sv[2][4];                                                            \
    _Pragma("unroll")                                                          \
    for (int h = 0; h < 2; ++h)                                                \
      _Pragma("unroll")                                                        \
      for (int kvt = 0; kvt < 4; ++kvt) sv[h][kvt] = (f32x4){0.f, 0.f, 0.f, 0.f}; \
    __builtin_amdgcn_s_setprio(1);                                             \
    _Pragma("unroll")                                                          \
    for (int kvt = 0; kvt < 4; ++kvt) {                                        \
      bf16x8 ka0 = *(const bf16x8*)(kb0 + (BUF) * 4096 + kvt * 1024);          \
      bf16x8 ka1 = *(const bf16x8*)(kb1 + (BUF) * 4096 + kvt * 1024);          \
      _Pragma("unroll")                                                        \
      for (int h = 0; h < 2; ++h) {                                            \
        sv[h][kvt] = __builtin_amdgcn_mfma_f32_16x16x32_bf16(ka0, qf[h][0], sv[h][kvt], 0, 0, 0); \
        sv[h][kvt] = __builtin_amdgcn_mfma_f32_16x16x32_bf16(ka1, qf[h][1], sv[h][kvt], 0, 0, 0); \
      }                                                                        \
    }                                                                          \
    __builtin_amdgcn_s_setprio(0);                                             \
    float tmax[2];                                                             \
    _Pragma("unroll")                                                          \
    for (int h = 0; h < 2; ++h) {                                              \
      float tm = sv[h][0][0];                                                  \
      _Pragma("unroll")                                                        \
      for (int kvt = 0; kvt < 4; ++kvt)                                        \
        _Pragma("unroll")                                                      \
        for (int r = 0; r < 4; ++r) tm = fmaxf(tm, sv[h][kvt][r]);             \
      tm = fmaxf(tm, __shfl_xor(tm, 16));                                      \
      tm = fmaxf(tm, __shfl_xor(tm, 32));                                      \
      tmax[h] = tm;                                                            \
    }                                                                          \
    float need = fmaxf(tmax[0] - mrun[0], tmax[1] - mrun[1]);                  \
    if (__any(need > THR)) {                                                   \
      _Pragma("unroll")                                                        \
      for (int h = 0; h < 2; ++h) {                                            \
        float mnew = fmaxf(mrun[h], tmax[h]);                                  \
        float alpha = fast_exp2(mrun[h] - mnew);                               \
        _Pragma("unroll")                                                      \
        for (int r = 0; r < 4; ++r) {                                          \
          float ar = __shfl(alpha, (lane & 48) + g * 4 + r);                   \
          lacc[h][r] *= ar;                                                    \
          _Pragma("unroll")                                                    \
          for (int dg = 0; dg < 4; ++dg) oacc[h][dg][r] *= ar;                 \
        }                                                                      \
        mrun[h] = mnew;                                                        \
      }                                                                        \
    }                                                                          \
    bf16x8 pa[2][2];                                                           \
    _Pragma("unroll")                                                          \
    for (int h = 0; h < 2; ++h) {                                              \
      float p[16];                                                             \
      _Pragma("unroll")                                                        \
      for (int kvt = 0; kvt < 4; ++kvt)                                        \
        _Pragma("unroll")                                                      \
        for (int r = 0; r < 4; ++r)                                            \
          p[kvt * 4 + r] = fast_exp2(sv[h][kvt][r] - mrun[h]);                 \
      uint2 pk;                                                                \
      pk.x = cvt_pk_bf16(p[0], p[1]);  pk.y = cvt_pk_bf16(p[2], p[3]);         \
      *(uint2*)&Psm[pw0] = pk;                                                 \
      pk.x = cvt_pk_bf16(p[4], p[5]);  pk.y = cvt_pk_bf16(p[6], p[7]);         \
      *(uint2*)&Psm[pw1] = pk;                                                 \
      pk.x = cvt_pk_bf16(p[8], p[9]);  pk.y = cvt_pk_bf16(p[10], p[11]);       \
      *(uint2*)&Psm[pw2] = pk;                                                 \
      pk.x = cvt_pk_bf16(p[12], p[13]); pk.y = cvt_pk_bf16(p[14], p[15]);      \
      *(uint2*)&Psm[pw3] = pk;                                                 \
      pa[h][0] = *(const bf16x8*)prb0;                                         \
      pa[h][1] = *(const bf16x8*)prb1;                                         \
    }                                                                          \
    __builtin_amdgcn_s_setprio(1);                                             \
    _Pragma("unroll")                                                          \
    for (int h = 0; h < 2; ++h) {                                              \
      lacc[h] = __builtin_amdgcn_mfma_f32_16x16x32_bf16(pa[h][0], onef.v, lacc[h], 0, 0, 0); \
      lacc[h] = __builtin_amdgcn_mfma_f32_16x16x32_bf16(pa[h][1], onef.v, lacc[h], 0, 0, 0); \
    }                                                                          \
    _Pragma("unroll")                                                          \
    for (int dg = 0; dg < 4; ++dg) {                                           \
      bf16x8 vb0 = *(const bf16x8*)(vrb0 + (BUF) * 4096 + dg * 1024);          \
      bf16x8 vb1 = *(const bf16x8*)(vrb1 + (BUF) * 4096 + dg * 1024);          \
      _Pragma("unroll")                                                        \
      for (int h = 0; h < 2; ++h) {                                            \
        oacc[h][dg] = __builtin_amdgcn_mfma_f32_16x16x32_bf16(pa[h][0], vb0, oacc[h][dg], 0, 0, 0); \
        oacc[h][dg] = __builtin_amdgcn_mfma_f32_16x16x32_bf16(pa[h][1], vb1, oacc[h][dg], 0, 0, 0); \
      }                                                                        \
    }                                                                          \
    __builtin_amdgcn_s_setprio(0);                                             \
    asm volatile("s_waitcnt vmcnt(0)" ::: "memory");                           \
    __builtin_amdgcn_s_barrier();                                              \
  } while (0)

  for (int tt = 0; tt < NKV / 2; ++tt) {
    ATTN_STEP(0);
    ATTN_STEP(1);
  }
#undef ATTN_STEP

  if constexpr (PARTIAL) {
    float* Op = Opart + (size_t)blockIdx.z * (SEQL * DMODEL);
    float* Lp = Lbuf + (size_t)blockIdx.z * (SEQL * HN * 2);
#pragma unroll
    for (int h = 0; h < 2; ++h)
#pragma unroll
      for (int r = 0; r < 4; ++r) {
        int row = q0 + h * 16 + g * 4 + r;
        float msh = __shfl(mrun[h], (lane & 48) + g * 4 + r); // all lanes exec
#pragma unroll
        for (int dg = 0; dg < 4; ++dg)
          Op[(size_t)row * DMODEL + hb + dg * 16 + qi] = oacc[h][dg][r];
        if (qi == 0) {
          Lp[(row * HN + blockIdx.y) * 2]     = lacc[h][r];
          Lp[(row * HN + blockIdx.y) * 2 + 1] = msh;
        }
      }
  } else {
#pragma unroll
    for (int h = 0; h < 2; ++h)
#pragma unroll
      for (int r = 0; r < 4; ++r) {
        float inv = 1.f / lacc[h][r];
        int row = q0 + h * 16 + g * 4 + r;
#pragma unroll
        for (int dg = 0; dg < 4; ++dg)
          Xm[(size_t)row * DMODEL + hb + dg * 16 + qi] = f2bf(oacc[h][dg][r] * inv);
      }
  }
}

// ---------------- combine the two KV-half partials -> bf16 Xp ---------------
__global__ __launch_bounds__(256) void attn_combine(
    const float* __restrict__ Opart, const float* __restrict__ Lbuf,
    unsigned short* __restrict__ Xm) {
  const int idx4 = blockIdx.x * 256 + threadIdx.x;   // 1048576 threads
  const int row = idx4 >> 8;
  const int col = (idx4 & 255) * 4;                  // 4 cols, same head
  const int head = col >> 6;
  float2 lm0 = ((const float2*)Lbuf)[row * HN + head];
  float2 lm1 = ((const float2*)(Lbuf + SEQL * HN * 2))[row * HN + head];
  float m = fmaxf(lm0.y, lm1.y);
  float w0 = fast_exp2(lm0.y - m), w1 = fast_exp2(lm1.y - m);
  float inv = 1.f / (lm0.x * w0 + lm1.x * w1);
  float4 o0 = *(const float4*)&Opart[(size_t)row * DMODEL + col];
  float4 o1 = *(const float4*)&Opart[(size_t)SEQL * DMODEL + (size_t)row * DMODEL + col];
  ushort4 res;
  res.x = f2bf((o0.x * w0 + o1.x * w1) * inv);
  res.y = f2bf((o0.y * w0 + o1.y * w1) * inv);
  res.z = f2bf((o0.z * w0 + o1.z * w1) * inv);
  res.w = f2bf((o0.w * w0 + o1.w * w1) * inv);
  *(ushort4*)&Xm[(size_t)row * DMODEL + col] = res;
}

// ---------------- launch ----------------
extern "C" void kernel_launch(void* const* d_in, const int* in_sizes, int n_in,
                              void* d_out, int out_size, void* d_ws, size_t ws_size,
                              hipStream_t stream) {
  const float* query = (const float*)d_in[0];
  const float* key_  = (const float*)d_in[1];
  const float* value = (const float*)d_in[2];
  const float* Wq = (const float*)d_in[3];
  const float* bq = (const float*)d_in[4];
  const float* Wk = (const float*)d_in[5];
  const float* bk = (const float*)d_in[6];
  const float* Wv = (const float*)d_in[7];
  const float* bv = (const float*)d_in[8];
  const float* Wo = (const float*)d_in[9];
  const float* bo = (const float*)d_in[10];

  char* ws = (char*)d_ws;
  const size_t MB = 1024 * 1024;
  unsigned short* qb  = (unsigned short*)(ws + 0 * MB);
  unsigned short* kb  = (unsigned short*)(ws + 8 * MB);
  unsigned short* vb  = (unsigned short*)(ws + 16 * MB);
  unsigned short* wqb = (unsigned short*)(ws + 24 * MB);
  unsigned short* wkb = (unsigned short*)(ws + 26 * MB);
  unsigned short* wvb = (unsigned short*)(ws + 28 * MB);
  unsigned short* wob = (unsigned short*)(ws + 30 * MB);
  unsigned short* Qp  = (unsigned short*)(ws + 32 * MB);
  unsigned short* Kp  = (unsigned short*)(ws + 40 * MB);
  unsigned short* Vtp = (unsigned short*)(ws + 48 * MB);
  unsigned short* Xp  = (unsigned short*)(ws + 56 * MB);
  float* Opart = (float*)(ws + 64 * MB);   // 2 x 16 MB (split path only)
  float* Lbuf  = (float*)(ws + 96 * MB);   // 2 x 512 KB (split path only)

  CvtArgs ca{query, key_, value, Wq, Wk, Wv, Wo, qb, kb, vb, wqb, wkb, wvb, wob};
  cvt_all<<<dim3(2048), dim3(256), 0, stream>>>(ca);

  const float CE = 0.18033688011112042f; // log2(e)/sqrt(64)
  GemmArgs gp;
  gp.d[0] = GemmDesc{qb, wqb, bq, (void*)Qp, 0, CE};   // Q pre-scaled
  gp.d[1] = GemmDesc{kb, wkb, bk, (void*)Kp, 0, 1.0f};
  gp.d[2] = GemmDesc{vb, wvb, bv, (void*)Vtp, 1, 1.0f}; // V transposed [d][s]
  gemm_bt<<<dim3(8, 32, 3), dim3(256), 0, stream>>>(gp);

  if (ws_size >= 98 * MB) {
    // KV-split x2: 1024 blocks -> 4 blocks/CU exactly (40KB LDS), no tail
    attn_fwd<true><<<dim3(SEQL / 128, HN, 2), dim3(256), 0, stream>>>(
        Qp, Kp, Vtp, nullptr, Opart, Lbuf);
    attn_combine<<<dim3(4096), dim3(256), 0, stream>>>(Opart, Lbuf, Xp);
  } else {
    attn_fwd<false><<<dim3(SEQL / 128, HN, 1), dim3(256), 0, stream>>>(
        Qp, Kp, Vtp, Xp, nullptr, nullptr);
  }

  gemm_o<<<dim3(16, 32), dim3(256), 0, stream>>>(Xp, wob, bo, (float*)d_out);
}